// Round 3
// baseline (1262.383 us; speedup 1.0000x reference)
//
#include <hip/hip_runtime.h>

#define BATCH 8
#define SLEN  2048
#define DDIM  512

typedef _Float16 f16;
typedef _Float16 half8  __attribute__((ext_vector_type(8)));
typedef _Float16 half4v __attribute__((ext_vector_type(4)));
typedef float    floatx4 __attribute__((ext_vector_type(4)));

// ---------------- pre-pass: K -> fp16 [B][S][D], V -> fp16 transposed [B][D][S] ----------------
__global__ __launch_bounds__(256) void prep_kernel(
    const float* __restrict__ Kin, const float* __restrict__ Vin,
    f16* __restrict__ Khg, f16* __restrict__ Vtg)
{
  __shared__ f16 vt[64][264];        // [d][s] tile, stride 264 (528B, 16B-aligned rows)
  const int tid = threadIdx.x;
  const int bid = blockIdx.x;
  if (bid < 8192) {
    // K convert: 8192 blocks * 256 threads * 1 float4
    const int i4 = bid * 256 + tid;
    float4 v = ((const float4*)Kin)[i4];
    half4v h;
    h.x = (f16)v.x; h.y = (f16)v.y; h.z = (f16)v.z; h.w = (f16)v.w;
    *(half4v*)(Khg + (size_t)i4 * 4) = h;
  } else {
    // V transpose: 512 blocks = 8 batches * 8 s-tiles(256) * 8 d-tiles(64)
    const int vb  = bid - 8192;
    const int b   = vb >> 6;
    const int rem = vb & 63;
    const int s0  = (rem >> 3) * 256;
    const int d0  = (rem & 7) * 64;
    const float* Vb = Vin + (size_t)b * SLEN * DDIM;
    const int d4 = (tid & 15) * 4;
    const int sb = (tid >> 4) * 4;
#pragma unroll
    for (int i = 0; i < 4; ++i) {
      const int ss = sb + i * 64;
      float fa[4][4];
#pragma unroll
      for (int j = 0; j < 4; ++j) {
        float4 f = *(const float4*)(Vb + (size_t)(s0 + ss + j) * DDIM + d0 + d4);
        fa[j][0] = f.x; fa[j][1] = f.y; fa[j][2] = f.z; fa[j][3] = f.w;
      }
#pragma unroll
      for (int k = 0; k < 4; ++k) {
        half4v hv;
        hv.x = (f16)fa[0][k]; hv.y = (f16)fa[1][k];
        hv.z = (f16)fa[2][k]; hv.w = (f16)fa[3][k];
        *(half4v*)&vt[d4 + k][ss] = hv;
      }
    }
    __syncthreads();
    f16* VtB = Vtg + (size_t)b * DDIM * SLEN;
#pragma unroll
    for (int i = 0; i < 8; ++i) {
      const int c   = tid + i * 256;
      const int rd  = c >> 5;
      const int sseg = c & 31;
      *(int4*)(VtB + (size_t)(d0 + rd) * SLEN + s0 + sseg * 8) = *(const int4*)&vt[rd][sseg * 8];
    }
  }
}

// ---------------- flash attention, no-barrier L2-streaming ----------------
// grid: 256 flat blocks, batch = bid&7 (XCD-local K/V), qtile = bid>>3.
// block 512 = 8 waves = (pid 0..3) x (h 0..1). Wave owns 16 q-rows (pid),
// half the keys (h), FULL n=512 private O + private online softmax (m,l).
// Main loop: K/V B-frags straight from global (L1/L2), zero __syncthreads().
// Epilogue: h-halves merge through LDS.
__global__ __launch_bounds__(512, 2) void attn_kernel(
    const float* __restrict__ Q, const f16* __restrict__ Khg,
    const f16* __restrict__ Vtg, float* __restrict__ Out)
{
  __shared__ f16   P_l[8][16][40];        // wave-private P round-trip (C->A layout)
  __shared__ float ml_l[4][2][2][16];     // [pid][h][{m,l}][row]
  __shared__ float Om[4][16][516];        // h=0 scaled O (pad 516: conflict-free)
  // LDS total: 10,240 + 512 + 132,096 = 142,848 B -> 1 block/CU, 8 waves

  const int tid  = threadIdx.x;
  const int lane = tid & 63;
  const int wave = tid >> 6;   // 0..7
  const int pid  = wave & 3;
  const int h    = wave >> 2;
  const int col  = lane & 15;
  const int quad = lane >> 4;
  const int bid  = blockIdx.x;
  const int b    = bid & 7;            // batch == XCD slot
  const int q0   = (bid >> 3) * 64 + pid * 16;

  const f16* KhB = Khg + (size_t)b * SLEN * DDIM;
  const f16* VtB = Vtg + (size_t)b * DDIM * SLEN;

  // Q A-frags (full D): A[m=col][k=quad*8+j], d = dc*32 + quad*8 + j
  half8 qf[16];
  {
    const float* Qr = Q + (size_t)(b * SLEN + q0 + col) * DDIM + quad * 8;
#pragma unroll
    for (int dc = 0; dc < 16; ++dc) {
      float4 f0 = *(const float4*)(Qr + dc * 32);
      float4 f1 = *(const float4*)(Qr + dc * 32 + 4);
      half8 hq;
      hq[0] = (f16)f0.x; hq[1] = (f16)f0.y; hq[2] = (f16)f0.z; hq[3] = (f16)f0.w;
      hq[4] = (f16)f1.x; hq[5] = (f16)f1.y; hq[6] = (f16)f1.z; hq[7] = (f16)f1.w;
      qf[dc] = hq;
    }
  }

  // ones B-frag: col 0 of the l-accumulator tile collects row-sums
  const f16 ov = (col == 0) ? (f16)1.0f : (f16)0.0f;
  const half8 ones = {ov, ov, ov, ov, ov, ov, ov, ov};

  const floatx4 fzero = {0.f, 0.f, 0.f, 0.f};
  floatx4 o[32];                       // 16 q-rows x 512 d, private
  floatx4 ol = fzero;
#pragma unroll
  for (int nb = 0; nb < 32; ++nb) o[nb] = fzero;
  float m_i[4] = {-3.0e38f, -3.0e38f, -3.0e38f, -3.0e38f};

  // per-lane streaming pointers (keys kb0 + kt*32 ...)
  const int kb0 = h * 1024;
  const f16* kp0 = KhB + (size_t)(kb0 + col) * DDIM + quad * 8;        // tile0 keys kb+col
  const f16* kp1 = kp0 + (size_t)16 * DDIM;                            // tile1 keys kb+16+col
  const f16* vp  = VtB + (size_t)col * SLEN + kb0 + quad * 8;          // d-row col, keys kb+quad*8

#pragma unroll 1
  for (int kt = 0; kt < 32; ++kt) {
    // ---- QK^T: 16q x 32k, depth 512; two independent acc chains ----
    floatx4 s0 = fzero, s1 = fzero;
#pragma unroll
    for (int dc = 0; dc < 16; ++dc) {
      half8 k0 = *(const half8*)(kp0 + dc * 32);   // imm offsets 0..960B
      half8 k1 = *(const half8*)(kp1 + dc * 32);
      s0 = __builtin_amdgcn_mfma_f32_16x16x32_f16(qf[dc], k0, s0, 0, 0, 0);
      s1 = __builtin_amdgcn_mfma_f32_16x16x32_f16(qf[dc], k1, s1, 0, 0, 0);
    }

    // ---- online softmax over this wave's 32 keys (row-groups are 16-lane) ----
    float al[4];
    int need = 0;
#pragma unroll
    for (int i = 0; i < 4; ++i) {
      float c = fmaxf(s0[i], s1[i]);
      c = fmaxf(c, __shfl_xor(c, 1));
      c = fmaxf(c, __shfl_xor(c, 2));
      c = fmaxf(c, __shfl_xor(c, 4));
      c = fmaxf(c, __shfl_xor(c, 8));
      float mn = fmaxf(m_i[i], c);
      al[i] = __expf(m_i[i] - mn);   // ==1 exactly when max unchanged
      m_i[i] = mn;
      need |= (al[i] != 1.0f);
    }
    if (__any(need)) {
#pragma unroll
      for (int nb = 0; nb < 32; ++nb) {
#pragma unroll
        for (int i = 0; i < 4; ++i) o[nb][i] *= al[i];
      }
#pragma unroll
      for (int i = 0; i < 4; ++i) ol[i] *= al[i];
    }

    // ---- P = exp(s-m): C-layout -> LDS -> A-layout (wave-private, no barrier) ----
#pragma unroll
    for (int i = 0; i < 4; ++i) {
      float p0 = __expf(s0[i] - m_i[i]);
      float p1 = __expf(s1[i] - m_i[i]);
      P_l[wave][quad * 4 + i][col]      = (f16)p0;
      P_l[wave][quad * 4 + i][col + 16] = (f16)p1;
    }
    half8 ap = *(const half8*)&P_l[wave][col][quad * 8];

    // ---- PV: O[16q][512d] += P(16x32) * V(32x512), V-frags from global ----
    const f16* vpl = vp;
#pragma unroll 8
    for (int nb = 0; nb < 32; ++nb) {
      half8 vf = *(const half8*)vpl;               // V^T[d=nb*16+col][keys kb+quad*8..]
      o[nb] = __builtin_amdgcn_mfma_f32_16x16x32_f16(ap, vf, o[nb], 0, 0, 0);
      vpl += (size_t)16 * SLEN;
    }
    ol = __builtin_amdgcn_mfma_f32_16x16x32_f16(ap, ones, ol, 0, 0, 0);

    kp0 += (size_t)32 * DDIM;
    kp1 += (size_t)32 * DDIM;
    vp  += 32;
  }

  // ---- epilogue: merge the two key-halves, divide by l, store ----
  if (col == 0) {
#pragma unroll
    for (int i = 0; i < 4; ++i) {
      ml_l[pid][h][0][quad * 4 + i] = m_i[i];
      ml_l[pid][h][1][quad * 4 + i] = ol[i];   // C[row][col0] = row-sum l
    }
  }
  __syncthreads();

  float sc[4], rl[4];
#pragma unroll
  for (int i = 0; i < 4; ++i) {
    const int r = quad * 4 + i;
    float m0 = ml_l[pid][0][0][r], m1 = ml_l[pid][1][0][r];
    float l0 = ml_l[pid][0][1][r], l1 = ml_l[pid][1][1][r];
    float mm = fmaxf(m0, m1);
    sc[i] = __expf(m_i[i] - mm);                       // this wave's rescale
    rl[i] = 1.0f / (__expf(m0 - mm) * l0 + __expf(m1 - mm) * l1);
  }

  if (h == 0) {
#pragma unroll
    for (int nb = 0; nb < 32; ++nb) {
#pragma unroll
      for (int i = 0; i < 4; ++i) {
        Om[pid][quad * 4 + i][nb * 16 + col] = o[nb][i] * sc[i];
      }
    }
  }
  __syncthreads();
  if (h == 1) {
    float* Ob = Out + (size_t)(b * SLEN + q0) * DDIM;
#pragma unroll
    for (int nb = 0; nb < 32; ++nb) {
#pragma unroll
      for (int i = 0; i < 4; ++i) {
        const int r = quad * 4 + i;
        float v = Om[pid][r][nb * 16 + col] + o[nb][i] * sc[i];
        Ob[(size_t)r * DDIM + nb * 16 + col] = v * rl[i];
      }
    }
  }
}

extern "C" void kernel_launch(void* const* d_in, const int* in_sizes, int n_in,
                              void* d_out, int out_size, void* d_ws, size_t ws_size,
                              hipStream_t stream) {
  const float* Qp = (const float*)d_in[0];
  const float* Kp = (const float*)d_in[1];
  const float* Vp = (const float*)d_in[2];
  float* Op = (float*)d_out;

  // ws: Khg fp16 [8][2048][512] (16 MiB) | Vtg fp16 [8][512][2048] (16 MiB)
  f16* Khg = (f16*)d_ws;
  f16* Vtg = (f16*)((char*)d_ws + (size_t)BATCH * SLEN * DDIM * sizeof(f16));

  prep_kernel<<<dim3(8192 + 512), dim3(256), 0, stream>>>(Kp, Vp, Khg, Vtg);
  attn_kernel<<<dim3(256), dim3(512), 0, stream>>>(Qp, Khg, Vtg, Op);
}

// Round 4
// 361.669 us; speedup vs baseline: 3.4904x; 3.4904x over previous
//
#include <hip/hip_runtime.h>

#define BATCH 8
#define SLEN  2048
#define DDIM  512

typedef _Float16 f16;
typedef _Float16 half8  __attribute__((ext_vector_type(8)));
typedef _Float16 half4v __attribute__((ext_vector_type(4)));
typedef float    floatx4 __attribute__((ext_vector_type(4)));

// async global->LDS DMA, 16 B/lane; LDS dest = wave-uniform base + lane*16
__device__ __forceinline__ void gld16(const f16* g, f16* l) {
  __builtin_amdgcn_global_load_lds(
      (const __attribute__((address_space(1))) void*)g,
      (__attribute__((address_space(3))) void*)l, 16, 0, 0);
}

// ---------------- pre-pass: K -> fp16 [B][S][D], V -> fp16 transposed [B][D][S] ----------------
__global__ __launch_bounds__(256) void prep_kernel(
    const float* __restrict__ Kin, const float* __restrict__ Vin,
    f16* __restrict__ Khg, f16* __restrict__ Vtg)
{
  __shared__ f16 vt[64][264];        // [d][s] tile, stride 264 f16 (bank phase (r+s)%8 even)
  const int tid = threadIdx.x;
  const int bid = blockIdx.x;
  if (bid < 1024) {
    // K convert: 1024 blocks * 256 thr * 8 float4
    const int base = bid * 2048 + tid;
#pragma unroll
    for (int i = 0; i < 8; ++i) {
      const int i4 = base + i * 256;
      float4 v = ((const float4*)Kin)[i4];
      half4v h;
      h.x = (f16)v.x; h.y = (f16)v.y; h.z = (f16)v.z; h.w = (f16)v.w;
      *(half4v*)(Khg + (size_t)i4 * 4) = h;
    }
  } else {
    // V transpose: 512 blocks = 8 batches * 8 s-tiles(256) * 8 d-tiles(64)
    const int vb  = bid - 1024;
    const int b   = vb >> 6;
    const int rem = vb & 63;
    const int s0  = (rem >> 3) * 256;
    const int d0  = (rem & 7) * 64;
    const float* Vb = Vin + (size_t)b * SLEN * DDIM;
    const int d4 = (tid & 15) * 4;
    const int sb = (tid >> 4) * 4;
#pragma unroll
    for (int i = 0; i < 4; ++i) {
      const int ss = sb + i * 64;
      float fa[4][4];
#pragma unroll
      for (int j = 0; j < 4; ++j) {
        float4 f = *(const float4*)(Vb + (size_t)(s0 + ss + j) * DDIM + d0 + d4);
        fa[j][0] = f.x; fa[j][1] = f.y; fa[j][2] = f.z; fa[j][3] = f.w;
      }
#pragma unroll
      for (int k = 0; k < 4; ++k) {
        half4v hv;
        hv.x = (f16)fa[0][k]; hv.y = (f16)fa[1][k];
        hv.z = (f16)fa[2][k]; hv.w = (f16)fa[3][k];
        *(half4v*)&vt[d4 + k][ss] = hv;
      }
    }
    __syncthreads();
    f16* VtB = Vtg + (size_t)b * DDIM * SLEN;
#pragma unroll
    for (int i = 0; i < 8; ++i) {
      const int c    = tid + i * 256;
      const int rd   = c >> 5;
      const int sseg = c & 31;
      *(int4*)(VtB + (size_t)(d0 + rd) * SLEN + s0 + sseg * 8) = *(const int4*)&vt[rd][sseg * 8];
    }
  }
}

// ---------------- flash attention: DMA-staged LDS, 8 waves = (pid 0..3) x (h 0..1) ----------------
// grid: 256 flat, batch = bid&7 (XCD-local KV), qtile = bid>>3 (64 q rows).
// Wave (pid,h): QK for pid's 16 q-rows vs key-half h; PV for pid's rows, d-half h, all 32 keys.
__global__ __launch_bounds__(512, 2) void attn_kernel(
    const float* __restrict__ Q, const f16* __restrict__ Khg,
    const f16* __restrict__ Vtg, float* __restrict__ Out)
{
  // LDS: K 2*33280 + V 2*32896 + P 5120 + pmax 512 = 138,688 B -> 1 block/CU
  __shared__ f16   Kh_l[2][32][520];   // [buf][key][d] rows 1040B; DMA writes first 1024B/row
  __shared__ f16   Vt_l[2][2056 * 8];  // [buf] chunk c = key8*514 + d, 16B chunks (planes padded +2)
  __shared__ f16   P_l[4][16][40];     // [pid][qrow][key 0..31]
  __shared__ float pmax[4][2][16];     // [pid][h][row] partial maxima

  const int tid  = threadIdx.x;
  const int lane = tid & 63;
  const int w    = tid >> 6;     // 0..7
  const int pid  = w & 3;
  const int h    = w >> 2;
  const int col  = lane & 15;
  const int quad = lane >> 4;
  const int bid  = blockIdx.x;
  const int b    = bid & 7;
  const int q0   = (bid >> 3) * 64 + pid * 16;

  const f16* KhB = Khg + (size_t)b * SLEN * DDIM;
  const f16* VtB = Vtg + (size_t)b * DDIM * SLEN;

  // Q A-frags (full D): A[m=col][k=quad*8+j], d = dc*32 + quad*8 + j
  half8 qf[16];
  {
    const float* Qr = Q + (size_t)(b * SLEN + q0 + col) * DDIM + quad * 8;
#pragma unroll
    for (int dc = 0; dc < 16; ++dc) {
      float4 f0 = *(const float4*)(Qr + dc * 32);
      float4 f1 = *(const float4*)(Qr + dc * 32 + 4);
      half8 hq;
      hq[0] = (f16)f0.x; hq[1] = (f16)f0.y; hq[2] = (f16)f0.z; hq[3] = (f16)f0.w;
      hq[4] = (f16)f1.x; hq[5] = (f16)f1.y; hq[6] = (f16)f1.z; hq[7] = (f16)f1.w;
      qf[dc] = hq;
    }
  }

  // ones B-frag: col 0 of l-acc tile collects row sums
  const f16 ov = (col == 0) ? (f16)1.0f : (f16)0.0f;
  const half8 ones = {ov, ov, ov, ov, ov, ov, ov, ov};

  const floatx4 fzero = {0.f, 0.f, 0.f, 0.f};
  floatx4 o[16];                   // 16 q-rows x 256 d (half h)
  floatx4 ol = fzero;
#pragma unroll
  for (int nt = 0; nt < 16; ++nt) o[nt] = fzero;
  float m_i[4] = {-3.0e38f, -3.0e38f, -3.0e38f, -3.0e38f};

  // ---- prologue: DMA tile 0 into buf 0 ----
#pragma unroll
  for (int i = 0; i < 4; ++i) {
    const int r = w + i * 8;
    gld16(KhB + (size_t)r * DDIM + lane * 8, &Kh_l[0][r][0]);
  }
#pragma unroll
  for (int i = 0; i < 4; ++i) {
    gld16(VtB + (size_t)(w * 64 + lane) * SLEN + i * 8, &Vt_l[0][(i * 514 + w * 64) * 8]);
  }
  __syncthreads();

  int buf = 0;
#pragma unroll 1
  for (int kt = 0; kt < 64; ++kt) {
    const int nb = buf ^ 1;
    // ---- async DMA tile kt+1 -> nb (nb's last readers finished before barrier #3 of kt-1) ----
    if (kt < 63) {
      const int k0n = (kt + 1) * 32;
#pragma unroll
      for (int i = 0; i < 4; ++i) {
        const int r = w + i * 8;
        gld16(KhB + (size_t)(k0n + r) * DDIM + lane * 8, &Kh_l[nb][r][0]);
      }
#pragma unroll
      for (int i = 0; i < 4; ++i) {
        gld16(VtB + (size_t)(w * 64 + lane) * SLEN + k0n + i * 8, &Vt_l[nb][(i * 514 + w * 64) * 8]);
      }
    }

    // ---- QK^T: pid's 16 q-rows vs keys h*16..h*16+15, depth 512 ----
    floatx4 s = fzero;
#pragma unroll
    for (int dc = 0; dc < 16; ++dc) {
      half8 kf = *(const half8*)&Kh_l[buf][h * 16 + col][dc * 32 + quad * 8];
      s = __builtin_amdgcn_mfma_f32_16x16x32_f16(qf[dc], kf, s, 0, 0, 0);
    }

    // ---- partial row-max over this wave's 16 keys ----
#pragma unroll
    for (int i = 0; i < 4; ++i) {
      float c = s[i];
      c = fmaxf(c, __shfl_xor(c, 1));
      c = fmaxf(c, __shfl_xor(c, 2));
      c = fmaxf(c, __shfl_xor(c, 4));
      c = fmaxf(c, __shfl_xor(c, 8));
      if (col == 0) pmax[pid][h][quad * 4 + i] = c;
    }
    __syncthreads();   // #1: pmax visible

    // ---- combine maxima, rescale O, P = exp(s-m) ----
    float al[4];
    int need = 0;
#pragma unroll
    for (int i = 0; i < 4; ++i) {
      const int r = quad * 4 + i;
      float m2 = fmaxf(pmax[pid][0][r], pmax[pid][1][r]);
      float mn = fmaxf(m_i[i], m2);
      al[i] = __expf(m_i[i] - mn);   // ==1 exactly when max unchanged
      m_i[i] = mn;
      need |= (al[i] != 1.0f);
    }
    if (__any(need)) {
#pragma unroll
      for (int nt = 0; nt < 16; ++nt) {
#pragma unroll
        for (int i = 0; i < 4; ++i) o[nt][i] *= al[i];
      }
#pragma unroll
      for (int i = 0; i < 4; ++i) ol[i] *= al[i];
    }
#pragma unroll
    for (int i = 0; i < 4; ++i) {
      float p = __expf(s[i] - m_i[i]);
      P_l[pid][quad * 4 + i][h * 16 + col] = (f16)p;
    }
    __syncthreads();   // #2: P visible (also drains this iter's DMA on each wave)

    // ---- PV: O[pid rows][d-half h] += P(16x32) * V(32x256) ----
    half8 ap = *(const half8*)&P_l[pid][col][quad * 8];
#pragma unroll
    for (int nt = 0; nt < 16; ++nt) {
      half8 vf = *(const half8*)&Vt_l[buf][(quad * 514 + h * 256 + nt * 16 + col) * 8];
      o[nt] = __builtin_amdgcn_mfma_f32_16x16x32_f16(ap, vf, o[nt], 0, 0, 0);
    }
    ol = __builtin_amdgcn_mfma_f32_16x16x32_f16(ap, ones, ol, 0, 0, 0);

    __syncthreads();   // #3: buf's readers done before next iter's DMA overwrites it
    buf = nb;
  }

  // ---- epilogue: divide by l (col 0 of ol tile) and store this wave's d-half ----
  float* Ob = Out + (size_t)(b * SLEN + q0) * DDIM;
#pragma unroll
  for (int i = 0; i < 4; ++i) {
    float li = __shfl(ol[i], (quad << 4));
    float rl = 1.0f / li;
#pragma unroll
    for (int nt = 0; nt < 16; ++nt) {
      Ob[(size_t)(quad * 4 + i) * DDIM + h * 256 + nt * 16 + col] = o[nt][i] * rl;
    }
  }
}

extern "C" void kernel_launch(void* const* d_in, const int* in_sizes, int n_in,
                              void* d_out, int out_size, void* d_ws, size_t ws_size,
                              hipStream_t stream) {
  const float* Qp = (const float*)d_in[0];
  const float* Kp = (const float*)d_in[1];
  const float* Vp = (const float*)d_in[2];
  float* Op = (float*)d_out;

  // ws: Khg fp16 [8][2048][512] (16 MiB) | Vtg fp16 [8][512][2048] (16 MiB)
  f16* Khg = (f16*)d_ws;
  f16* Vtg = (f16*)((char*)d_ws + (size_t)BATCH * SLEN * DDIM * sizeof(f16));

  prep_kernel<<<dim3(1024 + 512), dim3(256), 0, stream>>>(Kp, Vp, Khg, Vtg);
  attn_kernel<<<dim3(256), dim3(512), 0, stream>>>(Qp, Khg, Vtg, Op);
}

// Round 5
// 275.250 us; speedup vs baseline: 4.5863x; 1.3140x over previous
//
#include <hip/hip_runtime.h>

#define BATCH 8
#define SLEN  2048
#define DDIM  512
#define NQT   32   // 64-row q-tiles per batch

typedef _Float16 f16;
typedef _Float16 half8  __attribute__((ext_vector_type(8)));
typedef _Float16 half4v __attribute__((ext_vector_type(4)));
typedef float    floatx4 __attribute__((ext_vector_type(4)));

// async global->LDS DMA, 16 B/lane; LDS dest = wave-uniform base + lane*16
__device__ __forceinline__ void gld16(const f16* g, f16* l) {
  __builtin_amdgcn_global_load_lds(
      (const __attribute__((address_space(1))) void*)g,
      (__attribute__((address_space(3))) void*)l, 16, 0, 0);
}

// ---------------- pre-pass: K -> fp16 [B][S][D], V -> fp16 transposed [B][D][S] ----------------
__global__ __launch_bounds__(256) void prep_kernel(
    const float* __restrict__ Kin, const float* __restrict__ Vin,
    f16* __restrict__ Khg, f16* __restrict__ Vtg)
{
  __shared__ f16 vt[64][264];
  const int tid = threadIdx.x;
  const int bid = blockIdx.x;
  if (bid < 2048) {
    // K convert: 2048 blocks * 256 thr * 4 float4
    const int base = bid * 1024 + tid;
#pragma unroll
    for (int i = 0; i < 4; ++i) {
      const int i4 = base + i * 256;
      float4 v = ((const float4*)Kin)[i4];
      half4v h;
      h.x = (f16)v.x; h.y = (f16)v.y; h.z = (f16)v.z; h.w = (f16)v.w;
      *(half4v*)(Khg + (size_t)i4 * 4) = h;
    }
  } else {
    // V transpose: 512 blocks = 8 b * 8 s-tiles(256) * 8 d-tiles(64)
    const int vb  = bid - 2048;
    const int b   = vb >> 6;
    const int rem = vb & 63;
    const int s0  = (rem >> 3) * 256;
    const int d0  = (rem & 7) * 64;
    const float* Vb = Vin + (size_t)b * SLEN * DDIM;
    const int d4 = (tid & 15) * 4;
    const int sb = (tid >> 4) * 4;
#pragma unroll
    for (int i = 0; i < 4; ++i) {
      const int ss = sb + i * 64;
      float fa[4][4];
#pragma unroll
      for (int j = 0; j < 4; ++j) {
        float4 f = *(const float4*)(Vb + (size_t)(s0 + ss + j) * DDIM + d0 + d4);
        fa[j][0] = f.x; fa[j][1] = f.y; fa[j][2] = f.z; fa[j][3] = f.w;
      }
#pragma unroll
      for (int k = 0; k < 4; ++k) {
        half4v hv;
        hv.x = (f16)fa[0][k]; hv.y = (f16)fa[1][k];
        hv.z = (f16)fa[2][k]; hv.w = (f16)fa[3][k];
        *(half4v*)&vt[d4 + k][ss] = hv;
      }
    }
    __syncthreads();
    f16* VtB = Vtg + (size_t)b * DDIM * SLEN;
#pragma unroll
    for (int i = 0; i < 8; ++i) {
      const int c    = tid + i * 256;
      const int rd   = c >> 5;
      const int sseg = c & 31;
      *(int4*)(VtB + (size_t)(d0 + rd) * SLEN + s0 + sseg * 8) = *(const int4*)&vt[rd][sseg * 8];
    }
  }
}

// ---------------- flash attention, split-K: 512 blocks = 8 b * 32 qt * 2 kh ----------------
// block 256 thr = 4 waves (pid). Wave: 16 q-rows, ALL 32 keys of the tile, full d=512,
// fully private online softmax (no cross-wave exchange). 2 blocks/CU resident.
// Single K buf + single V buf, phase-offset DMA, 2 barriers/iter:
//   top:  DMA V(kt)      [V readers of kt-1 passed bar#B]   drains at bar#A
//   QK(kt) on K          [K(kt) DMA'd in kt-1, drained at bar#B(kt-1)]
//   bar#A
//   rescale, P, DMA K(kt+1) [K readers done at bar#A]       drains at bar#B
//   PV(kt) on V
//   bar#B
__global__ __launch_bounds__(256, 2) void attn_kernel(
    const float* __restrict__ Q, const f16* __restrict__ Khg,
    const f16* __restrict__ Vtg, float* __restrict__ O0,
    f16* __restrict__ O1, float* __restrict__ ML)
{
  __shared__ f16 K_l[32][520];       // 33,280 B ([key][d], DMA fills 1024 B/row)
  __shared__ f16 V_l[4 * 514 * 8];   // 32,896 B (chunk = plane(key8)*514 + d)
  __shared__ f16 P_l[4][16][40];     //  5,120 B (wave-private)
  // total 71,296 B -> 2 blocks/CU

  const int tid  = threadIdx.x;
  const int lane = tid & 63;
  const int w    = tid >> 6;    // pid 0..3
  const int col  = lane & 15;
  const int quad = lane >> 4;
  const int bid  = blockIdx.x;
  const int b    = bid & 7;            // batch == XCD slot (bid%8 round-robin)
  const int qt   = (bid >> 3) & 31;
  const int kh   = bid >> 8;           // key-half
  const int q0   = qt * 64 + w * 16;
  const int k00  = kh * 1024;

  const f16* KhB = Khg + (size_t)b * SLEN * DDIM;
  const f16* VtB = Vtg + (size_t)b * DDIM * SLEN;

  // Q A-frags (full D): A[m=col][k=quad*8+j], d = dc*32 + quad*8 + j
  half8 qf[16];
  {
    const float* Qr = Q + (size_t)(b * SLEN + q0 + col) * DDIM + quad * 8;
#pragma unroll
    for (int dc = 0; dc < 16; ++dc) {
      float4 f0 = *(const float4*)(Qr + dc * 32);
      float4 f1 = *(const float4*)(Qr + dc * 32 + 4);
      half8 hq;
      hq[0] = (f16)f0.x; hq[1] = (f16)f0.y; hq[2] = (f16)f0.z; hq[3] = (f16)f0.w;
      hq[4] = (f16)f1.x; hq[5] = (f16)f1.y; hq[6] = (f16)f1.z; hq[7] = (f16)f1.w;
      qf[dc] = hq;
    }
  }

  const f16 ov = (col == 0) ? (f16)1.0f : (f16)0.0f;
  const half8 ones = {ov, ov, ov, ov, ov, ov, ov, ov};

  const floatx4 fzero = {0.f, 0.f, 0.f, 0.f};
  floatx4 o[32];                      // 16 q x 512 d, private
  floatx4 ol = fzero;
#pragma unroll
  for (int nt = 0; nt < 32; ++nt) o[nt] = fzero;
  float m_i[4] = {-3.0e38f, -3.0e38f, -3.0e38f, -3.0e38f};

  // prologue: DMA K tile 0, drain
#pragma unroll
  for (int i = 0; i < 8; ++i) {
    const int r = w + i * 4;
    gld16(KhB + (size_t)(k00 + r) * DDIM + lane * 8, &K_l[r][0]);
  }
  __syncthreads();

#pragma unroll 1
  for (int kt = 0; kt < 32; ++kt) {
    const int kv0 = k00 + kt * 32;
    // ---- DMA V(kt): V_l free (PV(kt-1) readers passed bar#B) ----
#pragma unroll
    for (int i = 0; i < 8; ++i) {
      gld16(VtB + (size_t)(i * 64 + lane) * SLEN + kv0 + w * 8, &V_l[(w * 514 + i * 64) * 8]);
    }

    // ---- QK^T: 16 q x 32 keys, depth 512 ----
    floatx4 s0 = fzero, s1 = fzero;
#pragma unroll
    for (int dc = 0; dc < 16; ++dc) {
      half8 k0 = *(const half8*)&K_l[col][dc * 32 + quad * 8];
      half8 k1 = *(const half8*)&K_l[col + 16][dc * 32 + quad * 8];
      s0 = __builtin_amdgcn_mfma_f32_16x16x32_f16(qf[dc], k0, s0, 0, 0, 0);
      s1 = __builtin_amdgcn_mfma_f32_16x16x32_f16(qf[dc], k1, s1, 0, 0, 0);
    }

    // ---- wave-local online softmax over 32 keys ----
    float al[4];
    int need = 0;
#pragma unroll
    for (int i = 0; i < 4; ++i) {
      float c = fmaxf(s0[i], s1[i]);
      c = fmaxf(c, __shfl_xor(c, 1));
      c = fmaxf(c, __shfl_xor(c, 2));
      c = fmaxf(c, __shfl_xor(c, 4));
      c = fmaxf(c, __shfl_xor(c, 8));
      float mn = fmaxf(m_i[i], c);
      al[i] = __expf(m_i[i] - mn);   // ==1 exactly when max unchanged
      m_i[i] = mn;
      need |= (al[i] != 1.0f);
    }
    __syncthreads();   // bar#A: all K(kt) reads done; V(kt) DMA drained

    if (__any(need)) {
#pragma unroll
      for (int nt = 0; nt < 32; ++nt) {
#pragma unroll
        for (int i = 0; i < 4; ++i) o[nt][i] *= al[i];
      }
#pragma unroll
      for (int i = 0; i < 4; ++i) ol[i] *= al[i];
    }
#pragma unroll
    for (int i = 0; i < 4; ++i) {
      float p0 = __expf(s0[i] - m_i[i]);
      float p1 = __expf(s1[i] - m_i[i]);
      P_l[w][quad * 4 + i][col]      = (f16)p0;
      P_l[w][quad * 4 + i][col + 16] = (f16)p1;
    }
    half8 ap = *(const half8*)&P_l[w][col][quad * 8];   // wave-private round-trip

    // ---- DMA K(kt+1): K_l free since bar#A ----
    if (kt < 31) {
#pragma unroll
      for (int i = 0; i < 8; ++i) {
        const int r = w + i * 4;
        gld16(KhB + (size_t)(k00 + (kt + 1) * 32 + r) * DDIM + lane * 8, &K_l[r][0]);
      }
    }

    // ---- PV: O[16q][512d] += P(16x32) * V(32x512) ----
#pragma unroll
    for (int nt = 0; nt < 32; ++nt) {
      half8 vf = *(const half8*)&V_l[(quad * 514 + nt * 16 + col) * 8];
      o[nt] = __builtin_amdgcn_mfma_f32_16x16x32_f16(ap, vf, o[nt], 0, 0, 0);
    }
    ol = __builtin_amdgcn_mfma_f32_16x16x32_f16(ap, ones, ol, 0, 0, 0);

    __syncthreads();   // bar#B: V(kt) reads done; K(kt+1) DMA drained
  }

  // ---- epilogue: write partial (raw o', m, l) ----
  const size_t obase = (size_t)(b * SLEN + q0) * DDIM;
#pragma unroll
  for (int i = 0; i < 4; ++i) {
    const int r = quad * 4 + i;
    float li = __shfl(ol[i], (quad << 4));
    if (col == 0) {
      const int mlb = (((kh << 3) + b) * NQT + qt) * 128 + (w * 16 + r) * 2;
      ML[mlb]     = m_i[i];
      ML[mlb + 1] = li;
    }
    if (kh == 0) {
#pragma unroll
      for (int nt = 0; nt < 32; ++nt)
        O0[obase + (size_t)r * DDIM + nt * 16 + col] = o[nt][i];
    } else {
#pragma unroll
      for (int nt = 0; nt < 32; ++nt)
        O1[obase + (size_t)r * DDIM + nt * 16 + col] = (f16)o[nt][i];
    }
  }
}

// ---------------- merge: out = (w0*o0' + w1*o1') / (w0*l0 + w1*l1) ----------------
__global__ __launch_bounds__(256) void merge_kernel(
    float* __restrict__ O0, const f16* __restrict__ O1, const float* __restrict__ ML)
{
  __shared__ float wr[64][3];
  const int bid = blockIdx.x;        // 256 = b*32 + qt
  const int b = bid >> 5, qt = bid & 31;
  const int tid = threadIdx.x;
  if (tid < 64) {
    const int b0 = ((0 + b) * NQT + qt) * 128 + tid * 2;
    const int b1 = ((8 + b) * NQT + qt) * 128 + tid * 2;
    float m0 = ML[b0], l0 = ML[b0 + 1];
    float m1 = ML[b1], l1 = ML[b1 + 1];
    float mm = fmaxf(m0, m1);
    float w0 = __expf(m0 - mm), w1 = __expf(m1 - mm);
    wr[tid][0] = w0;
    wr[tid][1] = w1;
    wr[tid][2] = 1.0f / (w0 * l0 + w1 * l1);
  }
  __syncthreads();
  float*      Ob  = O0 + ((size_t)b * SLEN + qt * 64) * DDIM;
  const f16*  O1b = O1 + ((size_t)b * SLEN + qt * 64) * DDIM;
#pragma unroll 4
  for (int it = 0; it < 32; ++it) {
    const int e4 = it * 256 + tid;
    const int r  = e4 >> 7;            // 128 float4 per row
    const int d4 = (e4 & 127) * 4;
    float4 o0 = *(float4*)(Ob + (size_t)r * DDIM + d4);
    half4v o1 = *(const half4v*)(O1b + (size_t)r * DDIM + d4);
    const float w0 = wr[r][0], w1 = wr[r][1], rl = wr[r][2];
    float4 res;
    res.x = (o0.x * w0 + (float)o1.x * w1) * rl;
    res.y = (o0.y * w0 + (float)o1.y * w1) * rl;
    res.z = (o0.z * w0 + (float)o1.z * w1) * rl;
    res.w = (o0.w * w0 + (float)o1.w * w1) * rl;
    *(float4*)(Ob + (size_t)r * DDIM + d4) = res;
  }
}

extern "C" void kernel_launch(void* const* d_in, const int* in_sizes, int n_in,
                              void* d_out, int out_size, void* d_ws, size_t ws_size,
                              hipStream_t stream) {
  const float* Qp = (const float*)d_in[0];
  const float* Kp = (const float*)d_in[1];
  const float* Vp = (const float*)d_in[2];
  float* Op = (float*)d_out;

  // ws: Khg fp16 16 MiB | Vtg fp16 16 MiB | O1 fp16 16 MiB | ML fp32 256 KiB  (~48.3 MiB)
  f16*   Khg = (f16*)d_ws;
  f16*   Vtg = (f16*)((char*)d_ws + (size_t)16777216);
  f16*   O1  = (f16*)((char*)d_ws + (size_t)33554432);
  float* ML  = (float*)((char*)d_ws + (size_t)50331648);

  prep_kernel<<<dim3(2048 + 512), dim3(256), 0, stream>>>(Kp, Vp, Khg, Vtg);
  attn_kernel<<<dim3(512), dim3(256), 0, stream>>>(Qp, Khg, Vtg, Op, O1, ML);
  merge_kernel<<<dim3(256), dim3(256), 0, stream>>>(Op, O1, ML);
}